// Round 2
// baseline (1551.901 us; speedup 1.0000x reference)
//
#include <hip/hip_runtime.h>
#include <math.h>

// Dims (fixed by the problem)
#define Bv 4
#define Cv 256
#define Tv 64
#define Fv 256
#define Hv 8
#define HIDv 512
#define Mv 65536   // (B*T)*F rows

typedef unsigned short u16;

__device__ __forceinline__ float bf2f(u16 u) {
  return __uint_as_float(((unsigned int)u) << 16);
}
__device__ __forceinline__ u16 f2bf(float f) {
  // round-to-nearest-even bf16
  unsigned int x = __float_as_uint(f);
  unsigned int r = x + 0x7fffu + ((x >> 16) & 1u);
  return (u16)(r >> 16);
}

// ---------------- LN1 fused with (B,C,T,F) -> (M, C) transpose; bf16 out ----------------
__launch_bounds__(256)
__global__ void ln1_kernel(const float* __restrict__ x, const float* __restrict__ g,
                           const float* __restrict__ bta, u16* __restrict__ xn) {
  __shared__ float tile[256][33];
  __shared__ float red1[8][32];
  __shared__ float red2[8][32];
  __shared__ float mu_s[32];
  __shared__ float rs_s[32];
  const int tid = threadIdx.x;
  const int blk = blockIdx.x;
  const int n = blk >> 3;           // 0..255 sequence index
  const int f0 = (blk & 7) << 5;    // 0,32,...,224
  const int bb = n >> 6, tt = n & 63;
  const float* xb = x + (size_t)bb * (Cv * Tv * Fv) + (size_t)tt * Fv;
  const int fl = tid & 31, c0 = tid >> 5;
#pragma unroll
  for (int i = 0; i < 32; ++i) {
    int c = i * 8 + c0;
    tile[c][fl] = xb[(size_t)c * (Tv * Fv) + f0 + fl];
  }
  __syncthreads();
  const int col = tid & 31, part = tid >> 5;
  float s = 0.f, s2 = 0.f;
#pragma unroll
  for (int i = 0; i < 32; ++i) {
    float v = tile[part * 32 + i][col];
    s += v; s2 += v * v;
  }
  red1[part][col] = s; red2[part][col] = s2;
  __syncthreads();
  if (tid < 32) {
    float S1 = 0.f, S2 = 0.f;
#pragma unroll
    for (int p = 0; p < 8; ++p) { S1 += red1[p][tid]; S2 += red2[p][tid]; }
    float m = S1 * (1.f / 256.f);
    float var = S2 * (1.f / 256.f) - m * m;
    mu_s[tid] = m;
    rs_s[tid] = rsqrtf(var + 1e-5f);
  }
  __syncthreads();
  const float gv = g[tid], bv = bta[tid];
  u16* ob = xn + ((size_t)n * 256 + f0) * 256 + tid;
#pragma unroll
  for (int fl2 = 0; fl2 < 32; ++fl2) {
    ob[(size_t)fl2 * 256] = f2bf((tile[tid][fl2] - mu_s[fl2]) * rs_s[fl2] * gv + bv);
  }
}

// ---------------- generic GEMM, C[M,N] = A[M,K](bf16) @ B[K,N](f32) + epilogue ----------------
// EPI 0: plain store (bf16)
// EPI 1: + x residual (transposed gather from fp32 x), store bf16; aux0 = x
// EPI 2: gelu(acc + b1), store bf16; aux0 = b1
// EPI 3: acc + b2 + out1(bf16), store fp32 transposed to (B,C,T,F); aux0 = b2, aux1 = out1
template <int K, int N, int EPI>
__launch_bounds__(256)
__global__ void gemm_kernel(const u16* __restrict__ A, const float* __restrict__ Bw,
                            void* __restrict__ Cc, const float* __restrict__ aux0,
                            const u16* __restrict__ aux1) {
  constexpr int BM = 64, BN = 64, BK = 16;
  __shared__ float As[BK][BM + 4];
  __shared__ float Bs[BK][BN + 4];
  const int tid = threadIdx.x;
  const int m0 = blockIdx.y * BM, n0 = blockIdx.x * BN;
  const int a_m = tid >> 2, a_k4 = (tid & 3) << 2;
  const int b_k = tid >> 4, b_n4 = (tid & 15) << 2;
  const int tx = tid & 15, ty = tid >> 4;
  float acc[4][4] = {};
  for (int k0 = 0; k0 < K; k0 += BK) {
    ushort4 au = *(const ushort4*)(A + (size_t)(m0 + a_m) * K + k0 + a_k4);
    float4 bv = *(const float4*)(Bw + (size_t)(k0 + b_k) * N + n0 + b_n4);
    As[a_k4 + 0][a_m] = bf2f(au.x);
    As[a_k4 + 1][a_m] = bf2f(au.y);
    As[a_k4 + 2][a_m] = bf2f(au.z);
    As[a_k4 + 3][a_m] = bf2f(au.w);
    *(float4*)&Bs[b_k][b_n4] = bv;
    __syncthreads();
#pragma unroll
    for (int kk = 0; kk < BK; ++kk) {
      float4 a4 = *(const float4*)&As[kk][ty << 2];
      float4 b4 = *(const float4*)&Bs[kk][tx << 2];
      float ar[4] = {a4.x, a4.y, a4.z, a4.w};
      float br[4] = {b4.x, b4.y, b4.z, b4.w};
#pragma unroll
      for (int i = 0; i < 4; ++i)
#pragma unroll
        for (int j = 0; j < 4; ++j)
          acc[i][j] += ar[i] * br[j];
    }
    __syncthreads();
  }
#pragma unroll
  for (int i = 0; i < 4; ++i) {
    const int mrow = m0 + (ty << 2) + i;
    const int ncol0 = n0 + (tx << 2);
    if constexpr (EPI == 0) {
      ushort4 o = {f2bf(acc[i][0]), f2bf(acc[i][1]), f2bf(acc[i][2]), f2bf(acc[i][3])};
      *(ushort4*)((u16*)Cc + (size_t)mrow * N + ncol0) = o;
    } else if constexpr (EPI == 1) {
      const int nn = mrow >> 8, srow = mrow & 255;
      const int bb = nn >> 6, tt = nn & 63;
      const float* xrow = aux0 + (size_t)bb * (Cv * Tv * Fv) + (size_t)tt * Fv + srow;
      ushort4 o;
      o.x = f2bf(acc[i][0] + xrow[(size_t)(ncol0 + 0) * (Tv * Fv)]);
      o.y = f2bf(acc[i][1] + xrow[(size_t)(ncol0 + 1) * (Tv * Fv)]);
      o.z = f2bf(acc[i][2] + xrow[(size_t)(ncol0 + 2) * (Tv * Fv)]);
      o.w = f2bf(acc[i][3] + xrow[(size_t)(ncol0 + 3) * (Tv * Fv)]);
      *(ushort4*)((u16*)Cc + (size_t)mrow * N + ncol0) = o;
    } else if constexpr (EPI == 2) {
      ushort4 o;
      u16* po = (u16*)&o;
#pragma unroll
      for (int j = 0; j < 4; ++j) {
        float v = acc[i][j] + aux0[ncol0 + j];
        po[j] = f2bf(0.5f * v * (1.f + erff(v * 0.70710678118654752f)));
      }
      *(ushort4*)((u16*)Cc + (size_t)mrow * N + ncol0) = o;
    } else {  // EPI == 3: final residual + transposed fp32 store to d_out
      const int nn = mrow >> 8, srow = mrow & 255;
      const int bb = nn >> 6, tt = nn & 63;
      float* orow = (float*)Cc + (size_t)bb * (Cv * Tv * Fv) + (size_t)tt * Fv + srow;
#pragma unroll
      for (int j = 0; j < 4; ++j) {
        float r = bf2f(aux1[(size_t)mrow * 256 + ncol0 + j]);
        float v = acc[i][j] + aux0[ncol0 + j] + r;
        orow[(size_t)(ncol0 + j) * (Tv * Fv)] = v;
      }
    }
  }
}

// ---------------- attention: one block per (n, h); conv3 + l2norm fused into loads ----------------
__launch_bounds__(256)
__global__ void attn_kernel(const u16* __restrict__ qkv, const float* __restrict__ dw,
                            const float* __restrict__ temp, u16* __restrict__ attn_out) {
  // sK rows stored as 8 float4-groups, xor-swizzled by (row&7) so the per-thread
  // row-normalization phase isn't single-banked. sV plain (2-way is free).
  __shared__ float sK[256][32];
  __shared__ float sV[256][32];
  const int tid = threadIdx.x;
  const int n = blockIdx.x >> 3, h = blockIdx.x & 7;
  const int h32 = h * 32;
  const int jd = tid & 31;
  const int srow0 = tid >> 5;

  // ---- K and V: depthwise conv3 (pad 1) along seq, into LDS ----
  {
    const int chk = 256 + h32 + jd;
    const float wk0 = dw[chk * 3 + 0], wk1 = dw[chk * 3 + 1], wk2 = dw[chk * 3 + 2];
    const int chv = 512 + h32 + jd;
    const float wv0 = dw[chv * 3 + 0], wv1 = dw[chv * 3 + 1], wv2 = dw[chv * 3 + 2];
    const u16* srcK = qkv + (size_t)n * 256 * 768 + chk;
    const u16* srcV = qkv + (size_t)n * 256 * 768 + chv;
    const int g = jd >> 2, w = jd & 3;
#pragma unroll
    for (int i = 0; i < 32; ++i) {
      const int srow = i * 8 + srow0;
      const u16* pk = srcK + (size_t)srow * 768;
      float vk = wk1 * bf2f(pk[0]);
      if (srow > 0) vk += wk0 * bf2f(pk[-768]);
      if (srow < 255) vk += wk2 * bf2f(pk[768]);
      sK[srow][((g ^ (srow & 7)) << 2) + w] = vk;
      const u16* pv = srcV + (size_t)srow * 768;
      float vv = wv1 * bf2f(pv[0]);
      if (srow > 0) vv += wv0 * bf2f(pv[-768]);
      if (srow < 255) vv += wv2 * bf2f(pv[768]);
      sV[srow][jd] = vv;
    }
  }

  // ---- Q row (row index = tid): conv3 direct from global, l2norm in registers ----
  float q[32];
  {
    const u16* qb = qkv + ((size_t)n * 256 + tid) * 768 + h32;
    float ssq = 0.f;
#pragma unroll
    for (int j = 0; j < 32; ++j) {
      const int ch = h32 + j;
      const float w0 = dw[ch * 3 + 0], w1 = dw[ch * 3 + 1], w2 = dw[ch * 3 + 2];
      float v = w1 * bf2f(qb[j]);
      if (tid > 0) v += w0 * bf2f(qb[j - 768]);
      if (tid < 255) v += w2 * bf2f(qb[j + 768]);
      q[j] = v; ssq += v * v;
    }
    const float qinv = 1.f / fmaxf(sqrtf(ssq), 1e-12f);
#pragma unroll
    for (int j = 0; j < 32; ++j) q[j] *= qinv;
  }
  __syncthreads();

  // ---- l2-normalize K row tid in place ----
  {
    float kr[32];
    float ssk = 0.f;
    const int sw = tid & 7;
#pragma unroll
    for (int gg = 0; gg < 8; ++gg) {
      float4 kv = *(const float4*)&sK[tid][(gg ^ sw) << 2];
      kr[gg * 4 + 0] = kv.x; kr[gg * 4 + 1] = kv.y;
      kr[gg * 4 + 2] = kv.z; kr[gg * 4 + 3] = kv.w;
      ssk += kv.x * kv.x + kv.y * kv.y + kv.z * kv.z + kv.w * kv.w;
    }
    const float kinv = 1.f / fmaxf(sqrtf(ssk), 1e-12f);
#pragma unroll
    for (int gg = 0; gg < 8; ++gg) {
      float4 kv = {kr[gg * 4 + 0] * kinv, kr[gg * 4 + 1] * kinv,
                   kr[gg * 4 + 2] * kinv, kr[gg * 4 + 3] * kinv};
      *(float4*)&sK[tid][(gg ^ sw) << 2] = kv;
    }
  }
  __syncthreads();

  // ---- single-pass softmax (|qhat.khat*temp| <= |temp|, no max-sub needed) + PV ----
  const float th = temp[h];
  float accv[32] = {};
  float l = 0.f;
  for (int k = 0; k < 256; ++k) {
    const int swk = k & 7;
    float d0 = 0.f, d1 = 0.f, d2 = 0.f, d3 = 0.f;
#pragma unroll
    for (int gg = 0; gg < 8; ++gg) {
      float4 kv = *(const float4*)&sK[k][(gg ^ swk) << 2];
      d0 += q[gg * 4 + 0] * kv.x;
      d1 += q[gg * 4 + 1] * kv.y;
      d2 += q[gg * 4 + 2] * kv.z;
      d3 += q[gg * 4 + 3] * kv.w;
    }
    const float e = __expf(((d0 + d1) + (d2 + d3)) * th);
    l += e;
#pragma unroll
    for (int gg = 0; gg < 8; ++gg) {
      float4 vv = *(const float4*)&sV[k][gg << 2];
      accv[gg * 4 + 0] += e * vv.x;
      accv[gg * 4 + 1] += e * vv.y;
      accv[gg * 4 + 2] += e * vv.z;
      accv[gg * 4 + 3] += e * vv.w;
    }
  }
  const float linv = 1.f / l;
  u16* op = attn_out + ((size_t)n * 256 + tid) * 256 + h32;
#pragma unroll
  for (int gg = 0; gg < 8; ++gg) {
    ushort4 o = {f2bf(accv[gg * 4 + 0] * linv), f2bf(accv[gg * 4 + 1] * linv),
                 f2bf(accv[gg * 4 + 2] * linv), f2bf(accv[gg * 4 + 3] * linv)};
    *(ushort4*)(op + (gg << 2)) = o;
  }
}

// ---------------- LN2: wave per row, bf16 in/out ----------------
__launch_bounds__(256)
__global__ void ln2_kernel(const u16* __restrict__ in, const float* __restrict__ g,
                           const float* __restrict__ bta, u16* __restrict__ out) {
  const int lane = threadIdx.x & 63;
  const size_t row = (size_t)blockIdx.x * 4 + (threadIdx.x >> 6);
  const ushort4 u = ((const ushort4*)(in + row * 256))[lane];
  const float vx = bf2f(u.x), vy = bf2f(u.y), vz = bf2f(u.z), vw = bf2f(u.w);
  float s = vx + vy + vz + vw;
  float s2 = vx * vx + vy * vy + vz * vz + vw * vw;
#pragma unroll
  for (int m = 32; m >= 1; m >>= 1) {
    s += __shfl_xor(s, m, 64);
    s2 += __shfl_xor(s2, m, 64);
  }
  const float mu = s * (1.f / 256.f);
  const float rs = rsqrtf(s2 * (1.f / 256.f) - mu * mu + 1e-5f);
  const float4 gv = ((const float4*)g)[lane];
  const float4 bv = ((const float4*)bta)[lane];
  ushort4 o;
  o.x = f2bf((vx - mu) * rs * gv.x + bv.x);
  o.y = f2bf((vy - mu) * rs * gv.y + bv.y);
  o.z = f2bf((vz - mu) * rs * gv.z + bv.z);
  o.w = f2bf((vw - mu) * rs * gv.w + bv.w);
  ((ushort4*)(out + row * 256))[lane] = o;
}

extern "C" void kernel_launch(void* const* d_in, const int* in_sizes, int n_in,
                              void* d_out, int out_size, void* d_ws, size_t ws_size,
                              hipStream_t stream) {
  const float* x     = (const float*)d_in[0];
  const float* n1g   = (const float*)d_in[1];
  const float* n1b   = (const float*)d_in[2];
  const float* Wqkv  = (const float*)d_in[3];
  const float* dw    = (const float*)d_in[4];
  const float* Wproj = (const float*)d_in[5];
  const float* temp  = (const float*)d_in[6];
  const float* n2g   = (const float*)d_in[7];
  const float* n2b   = (const float*)d_in[8];
  const float* W1    = (const float*)d_in[9];
  const float* b1    = (const float*)d_in[10];
  const float* W2    = (const float*)d_in[11];
  const float* b2    = (const float*)d_in[12];

  // workspace (bf16 intermediates, peak 128 MiB):
  //   [0,  32M): xn -> attn_out -> xn2
  //   [32M,128M): qkv;  after attn: out1 at [32M,64M), h1 at [64M,128M)
  char* ws = (char*)d_ws;
  u16* xn       = (u16*)(ws);
  u16* qkv      = (u16*)(ws + (32ull << 20));
  u16* attn_out = xn;
  u16* out1     = (u16*)(ws + (32ull << 20));
  u16* xn2      = xn;
  u16* h1       = (u16*)(ws + (64ull << 20));

  ln1_kernel<<<2048, 256, 0, stream>>>(x, n1g, n1b, xn);
  gemm_kernel<256, 768, 0><<<dim3(12, 1024), 256, 0, stream>>>(xn, Wqkv, qkv, nullptr, nullptr);
  attn_kernel<<<2048, 256, 0, stream>>>(qkv, dw, temp, attn_out);
  gemm_kernel<256, 256, 1><<<dim3(4, 1024), 256, 0, stream>>>(attn_out, Wproj, out1, x, nullptr);
  ln2_kernel<<<16384, 256, 0, stream>>>(out1, n2g, n2b, xn2);
  gemm_kernel<256, 512, 2><<<dim3(8, 1024), 256, 0, stream>>>(xn2, W1, h1, b1, nullptr);
  gemm_kernel<512, 256, 3><<<dim3(4, 1024), 256, 0, stream>>>(h1, W2, d_out, b2, out1);
}

// Round 3
// 796.548 us; speedup vs baseline: 1.9483x; 1.9483x over previous
//
#include <hip/hip_runtime.h>
#include <math.h>

// Dims (fixed by the problem)
#define Bv 4
#define Cv 256
#define Tv 64
#define Fv 256
#define Hv 8
#define HIDv 512
#define Mv 65536   // (B*T)*F rows
#define CTF (Cv * Tv * Fv)
#define TF (Tv * Fv)

typedef unsigned short u16;
typedef __attribute__((ext_vector_type(8))) short bfx8;
typedef __attribute__((ext_vector_type(4))) float f32x4;

__device__ __forceinline__ float bf2f(u16 u) {
  return __uint_as_float(((unsigned int)u) << 16);
}
__device__ __forceinline__ u16 f2bf(float f) {
  unsigned int x = __float_as_uint(f);
  unsigned int r = x + 0x7fffu + ((x >> 16) & 1u);
  return (u16)(r >> 16);
}

// ---------------- one-shot weight transpose: fp32 [K][N] -> bf16 [N][K] ----------------
__launch_bounds__(256)
__global__ void transpose_w(const float* __restrict__ in, u16* __restrict__ out,
                            int K, int N) {
  __shared__ float t[32][33];
  const int n0 = blockIdx.x * 32, k0 = blockIdx.y * 32;
  const int c = threadIdx.x & 31, r = threadIdx.x >> 5;  // 32 cols x 8 rows
#pragma unroll
  for (int i = 0; i < 4; ++i)
    t[r + 8 * i][c] = in[(size_t)(k0 + r + 8 * i) * N + n0 + c];
  __syncthreads();
#pragma unroll
  for (int i = 0; i < 4; ++i)
    out[(size_t)(n0 + r + 8 * i) * K + k0 + c] = f2bf(t[c][r + 8 * i]);
}

// ---------------- LN1 fused with (B,C,T,F) -> (M, C) transpose; bf16 out ----------------
__launch_bounds__(256)
__global__ void ln1_kernel(const float* __restrict__ x, const float* __restrict__ g,
                           const float* __restrict__ bta, u16* __restrict__ xn) {
  __shared__ float tile[256][33];
  __shared__ float red1[8][32];
  __shared__ float red2[8][32];
  __shared__ float mu_s[32];
  __shared__ float rs_s[32];
  const int tid = threadIdx.x;
  const int blk = blockIdx.x;
  const int n = blk >> 3;           // 0..255 sequence index
  const int f0 = (blk & 7) << 5;    // 0,32,...,224
  const int bb = n >> 6, tt = n & 63;
  const float* xb = x + (size_t)bb * CTF + (size_t)tt * Fv;
  const int fl = tid & 31, c0 = tid >> 5;
#pragma unroll
  for (int i = 0; i < 32; ++i) {
    int c = i * 8 + c0;
    tile[c][fl] = xb[(size_t)c * TF + f0 + fl];
  }
  __syncthreads();
  const int col = tid & 31, part = tid >> 5;
  float s = 0.f, s2 = 0.f;
#pragma unroll
  for (int i = 0; i < 32; ++i) {
    float v = tile[part * 32 + i][col];
    s += v; s2 += v * v;
  }
  red1[part][col] = s; red2[part][col] = s2;
  __syncthreads();
  if (tid < 32) {
    float S1 = 0.f, S2 = 0.f;
#pragma unroll
    for (int p = 0; p < 8; ++p) { S1 += red1[p][tid]; S2 += red2[p][tid]; }
    float m = S1 * (1.f / 256.f);
    float var = S2 * (1.f / 256.f) - m * m;
    mu_s[tid] = m;
    rs_s[tid] = rsqrtf(var + 1e-5f);
  }
  __syncthreads();
  const float gv = g[tid], bv = bta[tid];
  u16* ob = xn + ((size_t)n * 256 + f0) * 256 + tid;
#pragma unroll
  for (int fl2 = 0; fl2 < 32; ++fl2) {
    ob[(size_t)fl2 * 256] = f2bf((tile[tid][fl2] - mu_s[fl2]) * rs_s[fl2] * gv + bv);
  }
}

// ---------------- MFMA GEMM: C[M,N] = A[M,K](bf16) @ Bt[N,K](bf16)^T + epilogue ----------
// 128x128 tile, BK=64, 256 threads = 4 waves, wave computes 64x64 via 4x4 MFMA frags.
// EPI 0: plain bf16 store
// EPI 1: + x residual (float4 gather from fp32 x), bf16 store; aux0 = x
// EPI 2: gelu(acc + b1) [tanh form], bf16 store; aux0 = b1
// EPI 3: acc + b2 + out1(bf16), fp32 float4 store transposed to (B,C,T,F); aux0=b2, aux1=out1
template <int K, int N, int EPI>
__launch_bounds__(256)
__global__ void gemm_mfma(const u16* __restrict__ A, const u16* __restrict__ Bt,
                          void* __restrict__ Cc, const float* __restrict__ aux0,
                          const u16* __restrict__ aux1) {
  constexpr int LDSTR = 88;  // u16 stride: 176 B, 16B-aligned, 2-way-free frag reads
  __shared__ u16 As[128 * LDSTR];
  __shared__ u16 Bs[128 * LDSTR];
  const int tid = threadIdx.x;
  const int lane = tid & 63, wid = tid >> 6;
  const int m0 = blockIdx.y * 128, n0 = blockIdx.x * 128;
  const int wm = (wid & 1) * 64, wn = (wid >> 1) * 64;
  const int lm = lane & 15, quad = lane >> 4;

  // staging map: chunk c in [0,1024): row = c>>3, ch = c&7 (8 bf16 per chunk)
  const int srow = tid >> 3, sch = tid & 7;

  f32x4 acc[4][4] = {};
  for (int k0 = 0; k0 < K; k0 += 64) {
    bfx8 ar[4], br[4];
#pragma unroll
    for (int i = 0; i < 4; ++i) {
      const int row = srow + i * 32;
      ar[i] = *(const bfx8*)(A + (size_t)(m0 + row) * K + k0 + sch * 8);
      br[i] = *(const bfx8*)(Bt + (size_t)(n0 + row) * K + k0 + sch * 8);
    }
    __syncthreads();
#pragma unroll
    for (int i = 0; i < 4; ++i) {
      const int row = srow + i * 32;
      *(bfx8*)&As[row * LDSTR + sch * 8] = ar[i];
      *(bfx8*)&Bs[row * LDSTR + sch * 8] = br[i];
    }
    __syncthreads();
#pragma unroll
    for (int s = 0; s < 2; ++s) {
      bfx8 af[4], bf[4];
#pragma unroll
      for (int t = 0; t < 4; ++t) {
        af[t] = *(const bfx8*)&As[(wm + t * 16 + lm) * LDSTR + s * 32 + quad * 8];
        bf[t] = *(const bfx8*)&Bs[(wn + t * 16 + lm) * LDSTR + s * 32 + quad * 8];
      }
#pragma unroll
      for (int tm = 0; tm < 4; ++tm)
#pragma unroll
        for (int tn = 0; tn < 4; ++tn)
          acc[tm][tn] = __builtin_amdgcn_mfma_f32_16x16x32_bf16(af[tm], bf[tn], acc[tm][tn], 0, 0, 0);
    }
  }

  // ---- epilogue ----
  const int row_l = quad * 4;
  const int nn = m0 >> 8;           // constant per block (128-tile never crosses 256)
  const int bb = nn >> 6, tt = nn & 63;
  const int srow_base = (m0 & 255) + wm;
  float bcol[4];
  if constexpr (EPI == 2 || EPI == 3) {
#pragma unroll
    for (int tn = 0; tn < 4; ++tn) bcol[tn] = aux0[n0 + wn + tn * 16 + lm];
  }
#pragma unroll
  for (int tm = 0; tm < 4; ++tm) {
    const int grow0 = m0 + wm + tm * 16 + row_l;
    const int sr0 = srow_base + tm * 16 + row_l;
#pragma unroll
    for (int tn = 0; tn < 4; ++tn) {
      const int gcol = n0 + wn + tn * 16 + lm;
      if constexpr (EPI == 0) {
#pragma unroll
        for (int r = 0; r < 4; ++r)
          ((u16*)Cc)[(size_t)(grow0 + r) * N + gcol] = f2bf(acc[tm][tn][r]);
      } else if constexpr (EPI == 1) {
        const float4 xv = *(const float4*)(aux0 + (size_t)bb * CTF + (size_t)gcol * TF + tt * Fv + sr0);
        const float xr[4] = {xv.x, xv.y, xv.z, xv.w};
#pragma unroll
        for (int r = 0; r < 4; ++r)
          ((u16*)Cc)[(size_t)(grow0 + r) * N + gcol] = f2bf(acc[tm][tn][r] + xr[r]);
      } else if constexpr (EPI == 2) {
#pragma unroll
        for (int r = 0; r < 4; ++r) {
          float v = acc[tm][tn][r] + bcol[tn];
          float y = 0.79788456080286536f * (v + 0.044715f * v * v * v);
          float th = 1.f - 2.f / (__expf(2.f * y) + 1.f);
          ((u16*)Cc)[(size_t)(grow0 + r) * N + gcol] = f2bf(0.5f * v * (1.f + th));
        }
      } else {  // EPI 3
        float4 o;
#pragma unroll
        for (int r = 0; r < 4; ++r) {
          float res = bf2f(aux1[(size_t)(grow0 + r) * 256 + gcol]);
          ((float*)&o)[r] = acc[tm][tn][r] + bcol[tn] + res;
        }
        *(float4*)((float*)Cc + (size_t)bb * CTF + (size_t)gcol * TF + tt * Fv + sr0) = o;
      }
    }
  }
}

// ---------------- attention: one block per (n, h); conv3 + l2norm fused into loads ----------------
__launch_bounds__(256)
__global__ void attn_kernel(const u16* __restrict__ qkv, const float* __restrict__ dw,
                            const float* __restrict__ temp, u16* __restrict__ attn_out) {
  __shared__ float sK[256][32];
  __shared__ float sV[256][32];
  const int tid = threadIdx.x;
  const int n = blockIdx.x >> 3, h = blockIdx.x & 7;
  const int h32 = h * 32;
  const int jd = tid & 31;
  const int srow0 = tid >> 5;

  {
    const int chk = 256 + h32 + jd;
    const float wk0 = dw[chk * 3 + 0], wk1 = dw[chk * 3 + 1], wk2 = dw[chk * 3 + 2];
    const int chv = 512 + h32 + jd;
    const float wv0 = dw[chv * 3 + 0], wv1 = dw[chv * 3 + 1], wv2 = dw[chv * 3 + 2];
    const u16* srcK = qkv + (size_t)n * 256 * 768 + chk;
    const u16* srcV = qkv + (size_t)n * 256 * 768 + chv;
    const int g = jd >> 2, w = jd & 3;
#pragma unroll
    for (int i = 0; i < 32; ++i) {
      const int srow = i * 8 + srow0;
      const u16* pk = srcK + (size_t)srow * 768;
      float vk = wk1 * bf2f(pk[0]);
      if (srow > 0) vk += wk0 * bf2f(pk[-768]);
      if (srow < 255) vk += wk2 * bf2f(pk[768]);
      sK[srow][((g ^ (srow & 7)) << 2) + w] = vk;
      const u16* pv = srcV + (size_t)srow * 768;
      float vv = wv1 * bf2f(pv[0]);
      if (srow > 0) vv += wv0 * bf2f(pv[-768]);
      if (srow < 255) vv += wv2 * bf2f(pv[768]);
      sV[srow][jd] = vv;
    }
  }

  float q[32];
  {
    const u16* qb = qkv + ((size_t)n * 256 + tid) * 768 + h32;
    float ssq = 0.f;
#pragma unroll
    for (int j = 0; j < 32; ++j) {
      const int ch = h32 + j;
      const float w0 = dw[ch * 3 + 0], w1 = dw[ch * 3 + 1], w2 = dw[ch * 3 + 2];
      float v = w1 * bf2f(qb[j]);
      if (tid > 0) v += w0 * bf2f(qb[j - 768]);
      if (tid < 255) v += w2 * bf2f(qb[j + 768]);
      q[j] = v; ssq += v * v;
    }
    const float qinv = 1.f / fmaxf(sqrtf(ssq), 1e-12f);
#pragma unroll
    for (int j = 0; j < 32; ++j) q[j] *= qinv;
  }
  __syncthreads();

  {
    float kr[32];
    float ssk = 0.f;
    const int sw = tid & 7;
#pragma unroll
    for (int gg = 0; gg < 8; ++gg) {
      float4 kv = *(const float4*)&sK[tid][(gg ^ sw) << 2];
      kr[gg * 4 + 0] = kv.x; kr[gg * 4 + 1] = kv.y;
      kr[gg * 4 + 2] = kv.z; kr[gg * 4 + 3] = kv.w;
      ssk += kv.x * kv.x + kv.y * kv.y + kv.z * kv.z + kv.w * kv.w;
    }
    const float kinv = 1.f / fmaxf(sqrtf(ssk), 1e-12f);
#pragma unroll
    for (int gg = 0; gg < 8; ++gg) {
      float4 kv = {kr[gg * 4 + 0] * kinv, kr[gg * 4 + 1] * kinv,
                   kr[gg * 4 + 2] * kinv, kr[gg * 4 + 3] * kinv};
      *(float4*)&sK[tid][(gg ^ sw) << 2] = kv;
    }
  }
  __syncthreads();

  const float th = temp[h];
  float accv[32] = {};
  float l = 0.f;
  for (int k = 0; k < 256; ++k) {
    const int swk = k & 7;
    float d0 = 0.f, d1 = 0.f, d2 = 0.f, d3 = 0.f;
#pragma unroll
    for (int gg = 0; gg < 8; ++gg) {
      float4 kv = *(const float4*)&sK[k][(gg ^ swk) << 2];
      d0 += q[gg * 4 + 0] * kv.x;
      d1 += q[gg * 4 + 1] * kv.y;
      d2 += q[gg * 4 + 2] * kv.z;
      d3 += q[gg * 4 + 3] * kv.w;
    }
    const float e = __expf(((d0 + d1) + (d2 + d3)) * th);
    l += e;
#pragma unroll
    for (int gg = 0; gg < 8; ++gg) {
      float4 vv = *(const float4*)&sV[k][gg << 2];
      accv[gg * 4 + 0] += e * vv.x;
      accv[gg * 4 + 1] += e * vv.y;
      accv[gg * 4 + 2] += e * vv.z;
      accv[gg * 4 + 3] += e * vv.w;
    }
  }
  const float linv = 1.f / l;
  u16* op = attn_out + ((size_t)n * 256 + tid) * 256 + h32;
#pragma unroll
  for (int gg = 0; gg < 8; ++gg) {
    ushort4 o = {f2bf(accv[gg * 4 + 0] * linv), f2bf(accv[gg * 4 + 1] * linv),
                 f2bf(accv[gg * 4 + 2] * linv), f2bf(accv[gg * 4 + 3] * linv)};
    *(ushort4*)(op + (gg << 2)) = o;
  }
}

// ---------------- LN2: wave per row, bf16 in/out ----------------
__launch_bounds__(256)
__global__ void ln2_kernel(const u16* __restrict__ in, const float* __restrict__ g,
                           const float* __restrict__ bta, u16* __restrict__ out) {
  const int lane = threadIdx.x & 63;
  const size_t row = (size_t)blockIdx.x * 4 + (threadIdx.x >> 6);
  const ushort4 u = ((const ushort4*)(in + row * 256))[lane];
  const float vx = bf2f(u.x), vy = bf2f(u.y), vz = bf2f(u.z), vw = bf2f(u.w);
  float s = vx + vy + vz + vw;
  float s2 = vx * vx + vy * vy + vz * vz + vw * vw;
#pragma unroll
  for (int m = 32; m >= 1; m >>= 1) {
    s += __shfl_xor(s, m, 64);
    s2 += __shfl_xor(s2, m, 64);
  }
  const float mu = s * (1.f / 256.f);
  const float rs = rsqrtf(s2 * (1.f / 256.f) - mu * mu + 1e-5f);
  const float4 gv = ((const float4*)g)[lane];
  const float4 bv = ((const float4*)bta)[lane];
  ushort4 o;
  o.x = f2bf((vx - mu) * rs * gv.x + bv.x);
  o.y = f2bf((vy - mu) * rs * gv.y + bv.y);
  o.z = f2bf((vz - mu) * rs * gv.z + bv.z);
  o.w = f2bf((vw - mu) * rs * gv.w + bv.w);
  ((ushort4*)(out + row * 256))[lane] = o;
}

extern "C" void kernel_launch(void* const* d_in, const int* in_sizes, int n_in,
                              void* d_out, int out_size, void* d_ws, size_t ws_size,
                              hipStream_t stream) {
  const float* x     = (const float*)d_in[0];
  const float* n1g   = (const float*)d_in[1];
  const float* n1b   = (const float*)d_in[2];
  const float* Wqkv  = (const float*)d_in[3];
  const float* dw    = (const float*)d_in[4];
  const float* Wproj = (const float*)d_in[5];
  const float* temp  = (const float*)d_in[6];
  const float* n2g   = (const float*)d_in[7];
  const float* n2b   = (const float*)d_in[8];
  const float* W1    = (const float*)d_in[9];
  const float* b1    = (const float*)d_in[10];
  const float* W2    = (const float*)d_in[11];
  const float* b2    = (const float*)d_in[12];

  // workspace (bf16 intermediates, peak 128 MiB):
  //   [0,  32M): xn -> attn_out -> xn2 -> (after MLP1) W2t stash
  //   [32M,128M): qkv;  after attn: out1 at [32M,64M), h1 at [64M,128M)
  char* ws = (char*)d_ws;
  u16* xn       = (u16*)(ws);
  u16* qkv      = (u16*)(ws + (32ull << 20));
  u16* attn_out = xn;
  u16* out1     = (u16*)(ws + (32ull << 20));
  u16* xn2      = xn;
  u16* h1       = (u16*)(ws + (64ull << 20));
  u16* w2t      = xn;  // xn region is dead after MLP1 reads xn2

  // transposed-weight stash in d_out (fully overwritten by the final GEMM)
  char* ob = (char*)d_out;
  u16* wqkvt  = (u16*)(ob);                 // 384 KiB
  u16* wprojt = (u16*)(ob + (1ull << 20));  // 128 KiB
  u16* w1t    = (u16*)(ob + 1572864ull);    // 256 KiB (at 1.5 MiB)

  transpose_w<<<dim3(24, 8), 256, 0, stream>>>(Wqkv, wqkvt, 256, 768);
  transpose_w<<<dim3(8, 8), 256, 0, stream>>>(Wproj, wprojt, 256, 256);
  transpose_w<<<dim3(16, 8), 256, 0, stream>>>(W1, w1t, 256, 512);

  ln1_kernel<<<2048, 256, 0, stream>>>(x, n1g, n1b, xn);
  gemm_mfma<256, 768, 0><<<dim3(6, 512), 256, 0, stream>>>(xn, wqkvt, qkv, nullptr, nullptr);
  attn_kernel<<<2048, 256, 0, stream>>>(qkv, dw, temp, attn_out);
  gemm_mfma<256, 256, 1><<<dim3(2, 512), 256, 0, stream>>>(attn_out, wprojt, out1, x, nullptr);
  ln2_kernel<<<16384, 256, 0, stream>>>(out1, n2g, n2b, xn2);
  gemm_mfma<256, 512, 2><<<dim3(4, 512), 256, 0, stream>>>(xn2, w1t, h1, b1, nullptr);
  transpose_w<<<dim3(8, 16), 256, 0, stream>>>(W2, w2t, 512, 256);
  gemm_mfma<512, 256, 3><<<dim3(2, 512), 256, 0, stream>>>(h1, w2t, d_out, b2, out1);
}

// Round 4
// 417.584 us; speedup vs baseline: 3.7164x; 1.9075x over previous
//
#include <hip/hip_runtime.h>
#include <math.h>

// Dims (fixed by the problem)
#define Bv 4
#define Cv 256
#define Tv 64
#define Fv 256
#define Hv 8
#define HIDv 512
#define Mv 65536   // (B*T)*F rows
#define CTF (Cv * Tv * Fv)
#define TF (Tv * Fv)

typedef unsigned short u16;
typedef __attribute__((ext_vector_type(8))) short bfx8;
typedef __attribute__((ext_vector_type(4))) float f32x4;

__device__ __forceinline__ float bf2f(u16 u) {
  return __uint_as_float(((unsigned int)u) << 16);
}
__device__ __forceinline__ u16 f2bf(float f) {
  unsigned int x = __float_as_uint(f);
  unsigned int r = x + 0x7fffu + ((x >> 16) & 1u);
  return (u16)(r >> 16);
}

// ---------------- one-shot weight transpose: fp32 [K][N] -> bf16 [N][K] ----------------
__launch_bounds__(256)
__global__ void transpose_w(const float* __restrict__ in, u16* __restrict__ out,
                            int K, int N) {
  __shared__ float t[32][33];
  const int n0 = blockIdx.x * 32, k0 = blockIdx.y * 32;
  const int c = threadIdx.x & 31, r = threadIdx.x >> 5;  // 32 cols x 8 rows
#pragma unroll
  for (int i = 0; i < 4; ++i)
    t[r + 8 * i][c] = in[(size_t)(k0 + r + 8 * i) * N + n0 + c];
  __syncthreads();
#pragma unroll
  for (int i = 0; i < 4; ++i)
    out[(size_t)(n0 + r + 8 * i) * K + k0 + c] = f2bf(t[c][r + 8 * i]);
}

// ---------------- LN1 fused with (B,C,T,F) -> (M, C) transpose; bf16 out ----------------
__launch_bounds__(256)
__global__ void ln1_kernel(const float* __restrict__ x, const float* __restrict__ g,
                           const float* __restrict__ bta, u16* __restrict__ xn) {
  __shared__ float tile[256][33];
  __shared__ float red1[8][32];
  __shared__ float red2[8][32];
  __shared__ float mu_s[32];
  __shared__ float rs_s[32];
  const int tid = threadIdx.x;
  const int blk = blockIdx.x;
  const int n = blk >> 3;           // 0..255 sequence index
  const int f0 = (blk & 7) << 5;    // 0,32,...,224
  const int bb = n >> 6, tt = n & 63;
  const float* xb = x + (size_t)bb * CTF + (size_t)tt * Fv;
  const int fl = tid & 31, c0 = tid >> 5;
#pragma unroll
  for (int i = 0; i < 32; ++i) {
    int c = i * 8 + c0;
    tile[c][fl] = xb[(size_t)c * TF + f0 + fl];
  }
  __syncthreads();
  const int col = tid & 31, part = tid >> 5;
  float s = 0.f, s2 = 0.f;
#pragma unroll
  for (int i = 0; i < 32; ++i) {
    float v = tile[part * 32 + i][col];
    s += v; s2 += v * v;
  }
  red1[part][col] = s; red2[part][col] = s2;
  __syncthreads();
  if (tid < 32) {
    float S1 = 0.f, S2 = 0.f;
#pragma unroll
    for (int p = 0; p < 8; ++p) { S1 += red1[p][tid]; S2 += red2[p][tid]; }
    float m = S1 * (1.f / 256.f);
    float var = S2 * (1.f / 256.f) - m * m;
    mu_s[tid] = m;
    rs_s[tid] = rsqrtf(var + 1e-5f);
  }
  __syncthreads();
  const float gv = g[tid], bv = bta[tid];
  u16* ob = xn + ((size_t)n * 256 + f0) * 256 + tid;
#pragma unroll
  for (int fl2 = 0; fl2 < 32; ++fl2) {
    ob[(size_t)fl2 * 256] = f2bf((tile[tid][fl2] - mu_s[fl2]) * rs_s[fl2] * gv + bv);
  }
}

// ---------------- MFMA GEMM: C[M,N] = A[M,K](bf16) @ Bt[N,K](bf16)^T + epilogue ----------
template <int K, int N, int EPI>
__launch_bounds__(256)
__global__ void gemm_mfma(const u16* __restrict__ A, const u16* __restrict__ Bt,
                          void* __restrict__ Cc, const float* __restrict__ aux0,
                          const u16* __restrict__ aux1) {
  constexpr int LDSTR = 88;  // u16 stride: 176 B, 16B-aligned, 2-way-free frag reads
  __shared__ u16 As[128 * LDSTR];
  __shared__ u16 Bs[128 * LDSTR];
  const int tid = threadIdx.x;
  const int lane = tid & 63, wid = tid >> 6;
  const int m0 = blockIdx.y * 128, n0 = blockIdx.x * 128;
  const int wm = (wid & 1) * 64, wn = (wid >> 1) * 64;
  const int lm = lane & 15, quad = lane >> 4;

  const int srow = tid >> 3, sch = tid & 7;

  f32x4 acc[4][4] = {};
  for (int k0 = 0; k0 < K; k0 += 64) {
    bfx8 ar[4], br[4];
#pragma unroll
    for (int i = 0; i < 4; ++i) {
      const int row = srow + i * 32;
      ar[i] = *(const bfx8*)(A + (size_t)(m0 + row) * K + k0 + sch * 8);
      br[i] = *(const bfx8*)(Bt + (size_t)(n0 + row) * K + k0 + sch * 8);
    }
    __syncthreads();
#pragma unroll
    for (int i = 0; i < 4; ++i) {
      const int row = srow + i * 32;
      *(bfx8*)&As[row * LDSTR + sch * 8] = ar[i];
      *(bfx8*)&Bs[row * LDSTR + sch * 8] = br[i];
    }
    __syncthreads();
#pragma unroll
    for (int s = 0; s < 2; ++s) {
      bfx8 af[4], bf[4];
#pragma unroll
      for (int t = 0; t < 4; ++t) {
        af[t] = *(const bfx8*)&As[(wm + t * 16 + lm) * LDSTR + s * 32 + quad * 8];
        bf[t] = *(const bfx8*)&Bs[(wn + t * 16 + lm) * LDSTR + s * 32 + quad * 8];
      }
#pragma unroll
      for (int tm = 0; tm < 4; ++tm)
#pragma unroll
        for (int tn = 0; tn < 4; ++tn)
          acc[tm][tn] = __builtin_amdgcn_mfma_f32_16x16x32_bf16(af[tm], bf[tn], acc[tm][tn], 0, 0, 0);
    }
  }

  const int row_l = quad * 4;
  const int nn = m0 >> 8;
  const int bb = nn >> 6, tt = nn & 63;
  const int srow_base = (m0 & 255) + wm;
  float bcol[4];
  if constexpr (EPI == 2 || EPI == 3) {
#pragma unroll
    for (int tn = 0; tn < 4; ++tn) bcol[tn] = aux0[n0 + wn + tn * 16 + lm];
  }
#pragma unroll
  for (int tm = 0; tm < 4; ++tm) {
    const int grow0 = m0 + wm + tm * 16 + row_l;
    const int sr0 = srow_base + tm * 16 + row_l;
#pragma unroll
    for (int tn = 0; tn < 4; ++tn) {
      const int gcol = n0 + wn + tn * 16 + lm;
      if constexpr (EPI == 0) {
#pragma unroll
        for (int r = 0; r < 4; ++r)
          ((u16*)Cc)[(size_t)(grow0 + r) * N + gcol] = f2bf(acc[tm][tn][r]);
      } else if constexpr (EPI == 1) {
        const float4 xv = *(const float4*)(aux0 + (size_t)bb * CTF + (size_t)gcol * TF + tt * Fv + sr0);
        const float xr[4] = {xv.x, xv.y, xv.z, xv.w};
#pragma unroll
        for (int r = 0; r < 4; ++r)
          ((u16*)Cc)[(size_t)(grow0 + r) * N + gcol] = f2bf(acc[tm][tn][r] + xr[r]);
      } else if constexpr (EPI == 2) {
#pragma unroll
        for (int r = 0; r < 4; ++r) {
          float v = acc[tm][tn][r] + bcol[tn];
          float y = 0.79788456080286536f * (v + 0.044715f * v * v * v);
          float th = 1.f - 2.f / (__expf(2.f * y) + 1.f);
          ((u16*)Cc)[(size_t)(grow0 + r) * N + gcol] = f2bf(0.5f * v * (1.f + th));
        }
      } else {  // EPI 3
        float4 o;
#pragma unroll
        for (int r = 0; r < 4; ++r) {
          float res = bf2f(aux1[(size_t)(grow0 + r) * 256 + gcol]);
          ((float*)&o)[r] = acc[tm][tn][r] + bcol[tn] + res;
        }
        *(float4*)((float*)Cc + (size_t)bb * CTF + (size_t)gcol * TF + tt * Fv + sr0) = o;
      }
    }
  }
}

// ---------------- MFMA flash attention: one block per (n,h), 4 waves ----------------
// S^T = Khat Qhat^T so that score C-frags (reg dim = keys) pack into b64 LDS
// writes of P[qrow][key] row-major = exactly the PV A-operand layout.
__launch_bounds__(256)
__global__ void attn_kernel(const u16* __restrict__ qkv, const float* __restrict__ dw,
                            const float* __restrict__ temp, u16* __restrict__ attn_out) {
  __shared__ u16 Qs[256 * 40];       // 20480 B, stride 40 u16 (80 B: 16B-aligned, 2-way)
  __shared__ u16 Kc[64 * 40];        // 5120 B
  __shared__ u16 Vtc[32 * 72];       // 4608 B, [d][key] stride 72 u16 (144 B)
  __shared__ u16 Pw[4 * 64 * 72];    // 36864 B, per-wave [qrow][key] stride 72
  __shared__ float l_s[256];         // per-wave row sums
  const int tid = threadIdx.x;
  const int lane = tid & 63, w = tid >> 6;
  const int l15 = lane & 15, quad = lane >> 4;
  const int n = blockIdx.x >> 3, h = blockIdx.x & 7;
  const int h32 = h * 32;
  const u16* base = qkv + (size_t)n * 256 * 768;
  const float th = temp[h];

  const int dg = tid & 3, d0 = dg * 8;
  const int rloc = tid >> 2;  // 0..63: 4 threads per row

  // ---- hoisted conv weights for this thread's 8 channels (K and V sections) ----
  float wtsK[3][8], wtsV[3][8];
#pragma unroll
  for (int j = 0; j < 8; ++j) {
    const int chk = 256 + h32 + d0 + j;
    const int chv = 512 + h32 + d0 + j;
#pragma unroll
    for (int t = 0; t < 3; ++t) {
      wtsK[t][j] = dw[chk * 3 + t];
      wtsV[t][j] = dw[chv * 3 + t];
    }
  }

  // ---- stage Q: conv3 + l2norm, 4 passes ----
  {
    float wtsQ[3][8];
#pragma unroll
    for (int j = 0; j < 8; ++j)
#pragma unroll
      for (int t = 0; t < 3; ++t) wtsQ[t][j] = dw[(h32 + d0 + j) * 3 + t];
#pragma unroll
    for (int p = 0; p < 4; ++p) {
      const int row = p * 64 + rloc;
      const u16* src = base + (size_t)row * 768 + h32 + d0;
      float v[8];
      const bfx8 bmid = *(const bfx8*)src;
#pragma unroll
      for (int j = 0; j < 8; ++j) v[j] = wtsQ[1][j] * bf2f((u16)bmid[j]);
      if (row > 0) {
        const bfx8 bprv = *(const bfx8*)(src - 768);
#pragma unroll
        for (int j = 0; j < 8; ++j) v[j] += wtsQ[0][j] * bf2f((u16)bprv[j]);
      }
      if (row < 255) {
        const bfx8 bnxt = *(const bfx8*)(src + 768);
#pragma unroll
        for (int j = 0; j < 8; ++j) v[j] += wtsQ[2][j] * bf2f((u16)bnxt[j]);
      }
      float ssq = 0.f;
#pragma unroll
      for (int j = 0; j < 8; ++j) ssq += v[j] * v[j];
      ssq += __shfl_xor(ssq, 1);
      ssq += __shfl_xor(ssq, 2);
      const float inv = 1.f / fmaxf(sqrtf(ssq), 1e-12f);
      bfx8 qb;
#pragma unroll
      for (int j = 0; j < 8; ++j) qb[j] = (short)f2bf(v[j] * inv);
      *(bfx8*)&Qs[row * 40 + d0] = qb;
    }
  }
  __syncthreads();

  // persistent Q B-frags: qrow = 64w + 16ct + l15, d = quad*8..+7
  bfx8 bq[4];
#pragma unroll
  for (int ct = 0; ct < 4; ++ct)
    bq[ct] = *(const bfx8*)&Qs[(w * 64 + ct * 16 + l15) * 40 + quad * 8];

  u16* PwB = Pw + w * (64 * 72);
  const f32x4 zf = {0.f, 0.f, 0.f, 0.f};
  f32x4 acc[4][2] = {};
  float lsum[4] = {0.f, 0.f, 0.f, 0.f};

  for (int c = 0; c < 4; ++c) {
    // ---- stage K-chunk (conv + l2norm) and V-chunk transposed ----
    {
      const int grow = c * 64 + rloc;
      const u16* srcK = base + (size_t)grow * 768 + 256 + h32 + d0;
      float v[8];
      const bfx8 bmid = *(const bfx8*)srcK;
#pragma unroll
      for (int j = 0; j < 8; ++j) v[j] = wtsK[1][j] * bf2f((u16)bmid[j]);
      if (grow > 0) {
        const bfx8 bprv = *(const bfx8*)(srcK - 768);
#pragma unroll
        for (int j = 0; j < 8; ++j) v[j] += wtsK[0][j] * bf2f((u16)bprv[j]);
      }
      if (grow < 255) {
        const bfx8 bnxt = *(const bfx8*)(srcK + 768);
#pragma unroll
        for (int j = 0; j < 8; ++j) v[j] += wtsK[2][j] * bf2f((u16)bnxt[j]);
      }
      float ssq = 0.f;
#pragma unroll
      for (int j = 0; j < 8; ++j) ssq += v[j] * v[j];
      ssq += __shfl_xor(ssq, 1);
      ssq += __shfl_xor(ssq, 2);
      const float inv = 1.f / fmaxf(sqrtf(ssq), 1e-12f);
      bfx8 kb;
#pragma unroll
      for (int j = 0; j < 8; ++j) kb[j] = (short)f2bf(v[j] * inv);
      *(bfx8*)&Kc[rloc * 40 + d0] = kb;

      const u16* srcV = base + (size_t)grow * 768 + 512 + h32 + d0;
      float vv[8];
      const bfx8 vmid = *(const bfx8*)srcV;
#pragma unroll
      for (int j = 0; j < 8; ++j) vv[j] = wtsV[1][j] * bf2f((u16)vmid[j]);
      if (grow > 0) {
        const bfx8 vprv = *(const bfx8*)(srcV - 768);
#pragma unroll
        for (int j = 0; j < 8; ++j) vv[j] += wtsV[0][j] * bf2f((u16)vprv[j]);
      }
      if (grow < 255) {
        const bfx8 vnxt = *(const bfx8*)(srcV + 768);
#pragma unroll
        for (int j = 0; j < 8; ++j) vv[j] += wtsV[2][j] * bf2f((u16)vnxt[j]);
      }
#pragma unroll
      for (int j = 0; j < 8; ++j) Vtc[(d0 + j) * 72 + rloc] = f2bf(vv[j]);
    }
    __syncthreads();

    // ---- scores: S^T tiles (key-tile rt x qrow-tile ct), exp, pack -> Pw ----
#pragma unroll
    for (int rt = 0; rt < 4; ++rt) {
      const bfx8 af = *(const bfx8*)&Kc[(rt * 16 + l15) * 40 + quad * 8];
#pragma unroll
      for (int ct = 0; ct < 4; ++ct) {
        f32x4 sc = __builtin_amdgcn_mfma_f32_16x16x32_bf16(af, bq[ct], zf, 0, 0, 0);
        float e0 = __expf(sc[0] * th);
        float e1 = __expf(sc[1] * th);
        float e2 = __expf(sc[2] * th);
        float e3 = __expf(sc[3] * th);
        lsum[ct] += (e0 + e1) + (e2 + e3);
        uint2 pk;
        pk.x = (unsigned int)f2bf(e0) | ((unsigned int)f2bf(e1) << 16);
        pk.y = (unsigned int)f2bf(e2) | ((unsigned int)f2bf(e3) << 16);
        *(uint2*)&PwB[(ct * 16 + l15) * 72 + rt * 16 + quad * 4] = pk;
      }
    }

    // ---- PV partial: O += P V over this chunk's 64 keys ----
#pragma unroll
    for (int ks = 0; ks < 2; ++ks) {
      const bfx8 bv0 = *(const bfx8*)&Vtc[l15 * 72 + ks * 32 + quad * 8];
      const bfx8 bv1 = *(const bfx8*)&Vtc[(16 + l15) * 72 + ks * 32 + quad * 8];
#pragma unroll
      for (int rt2 = 0; rt2 < 4; ++rt2) {
        const bfx8 ap = *(const bfx8*)&PwB[(rt2 * 16 + l15) * 72 + ks * 32 + quad * 8];
        acc[rt2][0] = __builtin_amdgcn_mfma_f32_16x16x32_bf16(ap, bv0, acc[rt2][0], 0, 0, 0);
        acc[rt2][1] = __builtin_amdgcn_mfma_f32_16x16x32_bf16(ap, bv1, acc[rt2][1], 0, 0, 0);
      }
    }
    __syncthreads();
  }

  // ---- softmax denominators: reduce across quads, stash per-wave ----
#pragma unroll
  for (int ct = 0; ct < 4; ++ct) {
    float L = lsum[ct];
    L += __shfl_xor(L, 16);
    L += __shfl_xor(L, 32);
    if (quad == 0) l_s[w * 64 + ct * 16 + l15] = L;
  }
  __syncthreads();

  // ---- epilogue: O /= l, store bf16 ----
#pragma unroll
  for (int rt2 = 0; rt2 < 4; ++rt2) {
    const f32x4 l4 = *(const f32x4*)&l_s[w * 64 + rt2 * 16 + quad * 4];
    float rinv[4];
#pragma unroll
    for (int r = 0; r < 4; ++r) rinv[r] = 1.f / l4[r];
#pragma unroll
    for (int ct2 = 0; ct2 < 2; ++ct2) {
#pragma unroll
      for (int r = 0; r < 4; ++r) {
        const int qrow = w * 64 + rt2 * 16 + quad * 4 + r;
        attn_out[((size_t)n * 256 + qrow) * 256 + h32 + ct2 * 16 + l15] =
            f2bf(acc[rt2][ct2][r] * rinv[r]);
      }
    }
  }
}

// ---------------- LN2: wave per row, bf16 in/out ----------------
__launch_bounds__(256)
__global__ void ln2_kernel(const u16* __restrict__ in, const float* __restrict__ g,
                           const float* __restrict__ bta, u16* __restrict__ out) {
  const int lane = threadIdx.x & 63;
  const size_t row = (size_t)blockIdx.x * 4 + (threadIdx.x >> 6);
  const ushort4 u = ((const ushort4*)(in + row * 256))[lane];
  const float vx = bf2f(u.x), vy = bf2f(u.y), vz = bf2f(u.z), vw = bf2f(u.w);
  float s = vx + vy + vz + vw;
  float s2 = vx * vx + vy * vy + vz * vz + vw * vw;
#pragma unroll
  for (int m = 32; m >= 1; m >>= 1) {
    s += __shfl_xor(s, m, 64);
    s2 += __shfl_xor(s2, m, 64);
  }
  const float mu = s * (1.f / 256.f);
  const float rs = rsqrtf(s2 * (1.f / 256.f) - mu * mu + 1e-5f);
  const float4 gv = ((const float4*)g)[lane];
  const float4 bv = ((const float4*)bta)[lane];
  ushort4 o;
  o.x = f2bf((vx - mu) * rs * gv.x + bv.x);
  o.y = f2bf((vy - mu) * rs * gv.y + bv.y);
  o.z = f2bf((vz - mu) * rs * gv.z + bv.z);
  o.w = f2bf((vw - mu) * rs * gv.w + bv.w);
  ((ushort4*)(out + row * 256))[lane] = o;
}

extern "C" void kernel_launch(void* const* d_in, const int* in_sizes, int n_in,
                              void* d_out, int out_size, void* d_ws, size_t ws_size,
                              hipStream_t stream) {
  const float* x     = (const float*)d_in[0];
  const float* n1g   = (const float*)d_in[1];
  const float* n1b   = (const float*)d_in[2];
  const float* Wqkv  = (const float*)d_in[3];
  const float* dw    = (const float*)d_in[4];
  const float* Wproj = (const float*)d_in[5];
  const float* temp  = (const float*)d_in[6];
  const float* n2g   = (const float*)d_in[7];
  const float* n2b   = (const float*)d_in[8];
  const float* W1    = (const float*)d_in[9];
  const float* b1    = (const float*)d_in[10];
  const float* W2    = (const float*)d_in[11];
  const float* b2    = (const float*)d_in[12];

  // workspace (bf16 intermediates, peak 128 MiB):
  //   [0,  32M): xn -> attn_out -> xn2 -> (after MLP1) W2t stash
  //   [32M,128M): qkv;  after attn: out1 at [32M,64M), h1 at [64M,128M)
  char* ws = (char*)d_ws;
  u16* xn       = (u16*)(ws);
  u16* qkv      = (u16*)(ws + (32ull << 20));
  u16* attn_out = xn;
  u16* out1     = (u16*)(ws + (32ull << 20));
  u16* xn2      = xn;
  u16* h1       = (u16*)(ws + (64ull << 20));
  u16* w2t      = xn;  // xn region is dead after MLP1 reads xn2

  // transposed-weight stash in d_out (fully overwritten by the final GEMM)
  char* ob = (char*)d_out;
  u16* wqkvt  = (u16*)(ob);                 // 384 KiB
  u16* wprojt = (u16*)(ob + (1ull << 20));  // 128 KiB
  u16* w1t    = (u16*)(ob + 1572864ull);    // 256 KiB (at 1.5 MiB)

  transpose_w<<<dim3(24, 8), 256, 0, stream>>>(Wqkv, wqkvt, 256, 768);
  transpose_w<<<dim3(8, 8), 256, 0, stream>>>(Wproj, wprojt, 256, 256);
  transpose_w<<<dim3(16, 8), 256, 0, stream>>>(W1, w1t, 256, 512);

  ln1_kernel<<<2048, 256, 0, stream>>>(x, n1g, n1b, xn);
  gemm_mfma<256, 768, 0><<<dim3(6, 512), 256, 0, stream>>>(xn, wqkvt, qkv, nullptr, nullptr);
  attn_kernel<<<2048, 256, 0, stream>>>(qkv, dw, temp, attn_out);
  gemm_mfma<256, 256, 1><<<dim3(2, 512), 256, 0, stream>>>(attn_out, wprojt, out1, x, nullptr);
  ln2_kernel<<<16384, 256, 0, stream>>>(out1, n2g, n2b, xn2);
  gemm_mfma<256, 512, 2><<<dim3(4, 512), 256, 0, stream>>>(xn2, W1 ? w1t : w1t, h1, b1, nullptr);
  transpose_w<<<dim3(8, 16), 256, 0, stream>>>(W2, w2t, 512, 256);
  gemm_mfma<512, 256, 3><<<dim3(2, 512), 256, 0, stream>>>(h1, w2t, d_out, b2, out1);
}